// Round 1
// baseline (413.498 us; speedup 1.0000x reference)
//
#include <hip/hip_runtime.h>
#include <hip/hip_bf16.h>
#include <cstdint>
#include <cstddef>

// Shapes fixed by the problem: B=4, N=16384, C=256, H=4, D=64.
#define SEQ   16384
#define CHN   256

typedef __attribute__((ext_vector_type(8))) short  short8;   // 8 bf16 (4 VGPRs)
typedef __attribute__((ext_vector_type(4))) float  f32x4;    // MFMA C/D

static __device__ __forceinline__ unsigned short f2bf(float f) {
    unsigned int u = __builtin_bit_cast(unsigned int, f);
    u += 0x7fffu + ((u >> 16) & 1u);            // round-to-nearest-even
    return (unsigned short)(u >> 16);
}
static __device__ __forceinline__ float bf2f(unsigned short h) {
    unsigned int u = ((unsigned int)h) << 16;
    return __builtin_bit_cast(float, u);
}
static __device__ __forceinline__ float gelu_exact(float x) {
    return 0.5f * x * (1.0f + erff(x * 0.70710678118654752f));
}
// XOR-swizzled ushort index for [R][64]-bf16 LDS tiles (128 B rows).
// Fixes the 16-lanes-same-bank pattern on ds_read_b128 (guide §6 G4).
static __device__ __forceinline__ int swz_us(int row, int kbyte) {
    return (row * 128 + (kbyte ^ ((row & 7) << 4))) >> 1;
}

// ---------------------------------------------------------------- prep ----
__global__ __launch_bounds__(256) void prep_kernel(
    const float* __restrict__ Wq, const float* __restrict__ Wk,
    const float* __restrict__ Wv, const float* __restrict__ Wp,
    unsigned short* __restrict__ Wqt, unsigned short* __restrict__ Wkt,
    unsigned short* __restrict__ Wvt, unsigned short* __restrict__ Wpt,
    float* __restrict__ KV, float* __restrict__ Ksum)
{
    const int idx = blockIdx.x * 256 + threadIdx.x;   // 0..65535
    const int n = idx >> 8, k = idx & 255;
    const int src = k * 256 + n;                      // W^T[n][k] = W[k][n]
    Wqt[idx] = f2bf(Wq[src]);
    Wkt[idx] = f2bf(Wk[src]);
    Wvt[idx] = f2bf(Wv[src]);
    Wpt[idx] = f2bf(Wp[src]);
    KV[idx] = 0.0f;                                   // 16*64*64 = 65536
    if (idx < 1024) Ksum[idx] = 0.0f;                 // 16*64
}

// ------------------------------------------------------------ QKV GEMM ----
// grid (6, 512): blockIdx.x = n-tile (mat = x>>1, col half = x&1), y = m-tile
__global__ __launch_bounds__(256) void qkv_gemm(
    const float* __restrict__ x, const float* __restrict__ my,
    const unsigned short* __restrict__ Wqt, const unsigned short* __restrict__ Wkt,
    const unsigned short* __restrict__ Wvt,
    const float* __restrict__ bq, const float* __restrict__ bk,
    const float* __restrict__ bv,
    unsigned short* __restrict__ Qb, unsigned short* __restrict__ Kb,
    unsigned short* __restrict__ Vb)
{
    __shared__ unsigned short As[128 * 64];
    __shared__ unsigned short Bs[128 * 64];
    const int t = threadIdx.x;
    const int mat  = blockIdx.x >> 1;
    const int col0 = (blockIdx.x & 1) * 128;
    const long row0 = (long)blockIdx.y * 128;
    const unsigned short* Wt = (mat == 0) ? Wqt : (mat == 1) ? Wkt : Wvt;
    const float* bias        = (mat == 0) ? bq  : (mat == 1) ? bk  : bv;

    const int lane = t & 63, wave = t >> 6;
    const int wm = wave >> 1, wn = wave & 1;

    f32x4 acc[4][4];
    #pragma unroll
    for (int i = 0; i < 4; ++i)
        #pragma unroll
        for (int j = 0; j < 4; ++j) acc[i][j] = (f32x4)0.0f;

    for (int k0 = 0; k0 < 256; k0 += 64) {
        // A tile: x (f32) -> bf16 LDS [128][64]
        #pragma unroll
        for (int it = 0; it < 8; ++it) {
            const int idx = it * 256 + t;
            const int r = idx >> 4, c4 = (idx & 15) * 4;
            const float4 v = *(const float4*)(x + (row0 + r) * 256 + k0 + c4);
            uint2 pk;
            pk.x = (unsigned int)f2bf(v.x) | ((unsigned int)f2bf(v.y) << 16);
            pk.y = (unsigned int)f2bf(v.z) | ((unsigned int)f2bf(v.w) << 16);
            *(uint2*)&As[swz_us(r, c4 * 2)] = pk;
        }
        // B tile: W^T rows (bf16) -> LDS [128][64]
        #pragma unroll
        for (int it = 0; it < 4; ++it) {
            const int idx = it * 256 + t;
            const int n = idx >> 3, c8 = (idx & 7) * 8;
            const uint4 v = *(const uint4*)(Wt + (size_t)(col0 + n) * 256 + k0 + c8);
            *(uint4*)&Bs[swz_us(n, c8 * 2)] = v;
        }
        __syncthreads();
        #pragma unroll
        for (int kk = 0; kk < 2; ++kk) {
            const int kbyte = kk * 64 + (lane >> 4) * 16;
            short8 af[4], bfr[4];
            #pragma unroll
            for (int mi = 0; mi < 4; ++mi) {
                const int r = wm * 64 + mi * 16 + (lane & 15);
                af[mi] = *(const short8*)&As[swz_us(r, kbyte)];
            }
            #pragma unroll
            for (int ni = 0; ni < 4; ++ni) {
                const int n = wn * 64 + ni * 16 + (lane & 15);
                bfr[ni] = *(const short8*)&Bs[swz_us(n, kbyte)];
            }
            #pragma unroll
            for (int mi = 0; mi < 4; ++mi)
                #pragma unroll
                for (int ni = 0; ni < 4; ++ni)
                    acc[mi][ni] = __builtin_amdgcn_mfma_f32_16x16x32_bf16(
                        af[mi], bfr[ni], acc[mi][ni], 0, 0, 0);
        }
        __syncthreads();
    }
    unsigned short* Ob = (mat == 0) ? Qb : (mat == 1) ? Kb : Vb;
    #pragma unroll
    for (int ni = 0; ni < 4; ++ni) {
        const int coll = col0 + wn * 64 + ni * 16 + (lane & 15);
        const float bc = bias[coll];
        #pragma unroll
        for (int mi = 0; mi < 4; ++mi) {
            const int lr0 = wm * 64 + mi * 16 + ((lane >> 4) << 2);
            #pragma unroll
            for (int r = 0; r < 4; ++r) {
                const long grow = row0 + lr0 + r;
                float val = acc[mi][ni][r] + bc;
                if (mat == 0)      val = gelu_exact(val) + 1.0f;
                else if (mat == 1) val = gelu_exact(val * my[grow]) + 1.0f;
                else               val = val * my[grow];
                Ob[grow * 256 + coll] = f2bf(val);
            }
        }
    }
}

// ----------------------------------------------------------- KV reduce ----
// grid (16, 16): x = m-chunk (1024 rows), y = (b*4+h). Vector FMA outer
// product; fp32 atomic accumulation into KV[bh][d][e] and Ksum[bh][d].
__global__ __launch_bounds__(256) void kv_reduce(
    const unsigned short* __restrict__ Kb, const unsigned short* __restrict__ Vb,
    float* __restrict__ KV, float* __restrict__ Ksum)
{
    __shared__ float kf[16][64];
    __shared__ float vf[16][64];
    const int t = threadIdx.x;
    const int bh = blockIdx.y;
    const long base = (long)(bh >> 2) * SEQ * 256 + (bh & 3) * 64;
    const long m0 = (long)blockIdx.x * 1024;
    const int d0 = (t >> 4) * 4, e0 = (t & 15) * 4;
    const int sr = t >> 4, swhich = (t >> 3) & 1, sseg = t & 7;
    float acc[4][4] = {};
    float ks[4] = {};
    for (int it = 0; it < 64; ++it) {
        const long row = m0 + it * 16 + sr;
        const unsigned short* src = (swhich ? Vb : Kb) + base + row * 256 + sseg * 8;
        const uint4 raw = *(const uint4*)src;
        const unsigned short* rh = (const unsigned short*)&raw;
        float* dst = swhich ? &vf[sr][sseg * 8] : &kf[sr][sseg * 8];
        #pragma unroll
        for (int j = 0; j < 8; ++j) dst[j] = bf2f(rh[j]);
        __syncthreads();
        #pragma unroll
        for (int mm = 0; mm < 16; ++mm) {
            const float4 kd = *(const float4*)&kf[mm][d0];
            const float4 ve = *(const float4*)&vf[mm][e0];
            const float k4[4] = {kd.x, kd.y, kd.z, kd.w};
            const float v4[4] = {ve.x, ve.y, ve.z, ve.w};
            #pragma unroll
            for (int i = 0; i < 4; ++i)
                #pragma unroll
                for (int j = 0; j < 4; ++j) acc[i][j] += k4[i] * v4[j];
            if ((t & 15) == 0) {
                #pragma unroll
                for (int i = 0; i < 4; ++i) ks[i] += k4[i];
            }
        }
        __syncthreads();
    }
    #pragma unroll
    for (int i = 0; i < 4; ++i)
        #pragma unroll
        for (int j = 0; j < 4; ++j)
            atomicAdd(&KV[((size_t)bh * 64 + d0 + i) * 64 + e0 + j], acc[i][j]);
    if ((t & 15) == 0) {
        #pragma unroll
        for (int i = 0; i < 4; ++i) atomicAdd(&Ksum[bh * 64 + d0 + i], ks[i]);
    }
}

// ---------------------------------------------------------------- attn ----
// grid (512): one 128-row tile; loops the 4 heads. attn = (Q@KV)*mx/denom.
__global__ __launch_bounds__(256) void attn_kernel(
    const unsigned short* __restrict__ Qb, const float* __restrict__ KV,
    const float* __restrict__ Ksum, const float* __restrict__ mx,
    unsigned short* __restrict__ Ab)
{
    __shared__ unsigned short Qs[128 * 64];
    __shared__ unsigned short KVT[64 * 64];
    __shared__ float ksh[64];
    __shared__ float sden[128];
    const int t = threadIdx.x;
    const long row0 = (long)blockIdx.x * 128;
    const int b = (int)(row0 >> 14);
    const int lane = t & 63, wave = t >> 6, wm = wave >> 1, wn = wave & 1;

    for (int h = 0; h < 4; ++h) {
        const int bh = b * 4 + h;
        // stage Q_h [128][64]
        #pragma unroll
        for (int it = 0; it < 4; ++it) {
            const int idx = it * 256 + t;
            const int r = idx >> 3, c8 = (idx & 7) * 8;
            const uint4 v = *(const uint4*)(Qb + (row0 + r) * 256 + h * 64 + c8);
            *(uint4*)&Qs[swz_us(r, c8 * 2)] = v;
        }
        // stage KV^T [e][d] (bf16, swizzled)
        {
            const int e = t & 63, dg = t >> 6;
            #pragma unroll
            for (int i = 0; i < 16; ++i) {
                const int d = dg * 16 + i;
                const float v = KV[((size_t)bh * 64 + d) * 64 + e];
                KVT[(e * 128 + ((d * 2) ^ ((e & 7) << 4))) >> 1] = f2bf(v);
            }
        }
        if (t < 64) ksh[t] = Ksum[bh * 64 + t];
        __syncthreads();
        // denom per row; sden = mask_x / denom
        if (t < 128) {
            float s = 0.0f;
            for (int d = 0; d < 64; ++d)
                s += bf2f(Qs[swz_us(t, d * 2)]) * ksh[d];
            sden[t] = mx[row0 + t] / s;
        }
        __syncthreads();
        // MFMA: per wave 64m x 32e, k = 64 (two K=32 steps)
        f32x4 acc[4][2];
        #pragma unroll
        for (int i = 0; i < 4; ++i) { acc[i][0] = (f32x4)0.0f; acc[i][1] = (f32x4)0.0f; }
        #pragma unroll
        for (int kk = 0; kk < 2; ++kk) {
            const int kbyte = kk * 64 + (lane >> 4) * 16;
            short8 af[4], bfr[2];
            #pragma unroll
            for (int mi = 0; mi < 4; ++mi) {
                const int r = wm * 64 + mi * 16 + (lane & 15);
                af[mi] = *(const short8*)&Qs[swz_us(r, kbyte)];
            }
            #pragma unroll
            for (int ni = 0; ni < 2; ++ni) {
                const int e = wn * 32 + ni * 16 + (lane & 15);
                bfr[ni] = *(const short8*)&KVT[swz_us(e, kbyte)];
            }
            #pragma unroll
            for (int mi = 0; mi < 4; ++mi)
                #pragma unroll
                for (int ni = 0; ni < 2; ++ni)
                    acc[mi][ni] = __builtin_amdgcn_mfma_f32_16x16x32_bf16(
                        af[mi], bfr[ni], acc[mi][ni], 0, 0, 0);
        }
        #pragma unroll
        for (int ni = 0; ni < 2; ++ni) {
            const int e = wn * 32 + ni * 16 + (lane & 15);
            #pragma unroll
            for (int mi = 0; mi < 4; ++mi) {
                const int lr0 = wm * 64 + mi * 16 + ((lane >> 4) << 2);
                #pragma unroll
                for (int r = 0; r < 4; ++r) {
                    const int lr = lr0 + r;
                    const float val = acc[mi][ni][r] * sden[lr];
                    Ab[(row0 + lr) * 256 + h * 64 + e] = f2bf(val);
                }
            }
        }
        __syncthreads();   // LDS reused next head
    }
}

// ------------------------------------------------------------ out proj ----
// grid (2, 512): y = attn @ Wp + bp, f32 out
__global__ __launch_bounds__(256) void proj_gemm(
    const unsigned short* __restrict__ Ab, const unsigned short* __restrict__ Wpt,
    const float* __restrict__ bp, float* __restrict__ out)
{
    __shared__ unsigned short As[128 * 64];
    __shared__ unsigned short Bs[128 * 64];
    const int t = threadIdx.x;
    const int col0 = blockIdx.x * 128;
    const long row0 = (long)blockIdx.y * 128;
    const int lane = t & 63, wave = t >> 6, wm = wave >> 1, wn = wave & 1;

    f32x4 acc[4][4];
    #pragma unroll
    for (int i = 0; i < 4; ++i)
        #pragma unroll
        for (int j = 0; j < 4; ++j) acc[i][j] = (f32x4)0.0f;

    for (int k0 = 0; k0 < 256; k0 += 64) {
        #pragma unroll
        for (int it = 0; it < 4; ++it) {
            const int idx = it * 256 + t;
            const int r = idx >> 3, c8 = (idx & 7) * 8;
            const uint4 v = *(const uint4*)(Ab + (row0 + r) * 256 + k0 + c8);
            *(uint4*)&As[swz_us(r, c8 * 2)] = v;
        }
        #pragma unroll
        for (int it = 0; it < 4; ++it) {
            const int idx = it * 256 + t;
            const int n = idx >> 3, c8 = (idx & 7) * 8;
            const uint4 v = *(const uint4*)(Wpt + (size_t)(col0 + n) * 256 + k0 + c8);
            *(uint4*)&Bs[swz_us(n, c8 * 2)] = v;
        }
        __syncthreads();
        #pragma unroll
        for (int kk = 0; kk < 2; ++kk) {
            const int kbyte = kk * 64 + (lane >> 4) * 16;
            short8 af[4], bfr[4];
            #pragma unroll
            for (int mi = 0; mi < 4; ++mi) {
                const int r = wm * 64 + mi * 16 + (lane & 15);
                af[mi] = *(const short8*)&As[swz_us(r, kbyte)];
            }
            #pragma unroll
            for (int ni = 0; ni < 4; ++ni) {
                const int n = wn * 64 + ni * 16 + (lane & 15);
                bfr[ni] = *(const short8*)&Bs[swz_us(n, kbyte)];
            }
            #pragma unroll
            for (int mi = 0; mi < 4; ++mi)
                #pragma unroll
                for (int ni = 0; ni < 4; ++ni)
                    acc[mi][ni] = __builtin_amdgcn_mfma_f32_16x16x32_bf16(
                        af[mi], bfr[ni], acc[mi][ni], 0, 0, 0);
        }
        __syncthreads();
    }
    #pragma unroll
    for (int ni = 0; ni < 4; ++ni) {
        const int coll = col0 + wn * 64 + ni * 16 + (lane & 15);
        const float bc = bp[coll];
        #pragma unroll
        for (int mi = 0; mi < 4; ++mi) {
            const int lr0 = wm * 64 + mi * 16 + ((lane >> 4) << 2);
            #pragma unroll
            for (int r = 0; r < 4; ++r) {
                const long grow = row0 + lr0 + r;
                out[grow * 256 + coll] = acc[mi][ni][r] + bc;
            }
        }
    }
}

// -------------------------------------------------------------- launch ----
extern "C" void kernel_launch(void* const* d_in, const int* in_sizes, int n_in,
                              void* d_out, int out_size, void* d_ws, size_t ws_size,
                              hipStream_t stream)
{
    (void)in_sizes; (void)n_in; (void)out_size; (void)ws_size;
    const float* x  = (const float*)d_in[0];
    const float* mx = (const float*)d_in[1];
    const float* my = (const float*)d_in[2];
    const float* Wq = (const float*)d_in[3];
    const float* bq = (const float*)d_in[4];
    const float* Wk = (const float*)d_in[5];
    const float* bk = (const float*)d_in[6];
    const float* Wv = (const float*)d_in[7];
    const float* bv = (const float*)d_in[8];
    const float* Wp = (const float*)d_in[9];
    const float* bp = (const float*)d_in[10];
    float* out = (float*)d_out;

    const size_t nelem = (size_t)4 * SEQ * CHN;      // 16,777,216
    char* w = (char*)d_ws;
    unsigned short* Qb  = (unsigned short*)w; w += nelem * 2;
    unsigned short* Kb  = (unsigned short*)w; w += nelem * 2;
    unsigned short* Vb  = (unsigned short*)w; w += nelem * 2;
    unsigned short* Wqt = (unsigned short*)w; w += 131072;
    unsigned short* Wkt = (unsigned short*)w; w += 131072;
    unsigned short* Wvt = (unsigned short*)w; w += 131072;
    unsigned short* Wpt = (unsigned short*)w; w += 131072;
    float* KV   = (float*)w; w += 262144;
    float* Ksum = (float*)w; w += 4096;
    unsigned short* Ab = Kb;   // alias: Kb is dead after kv_reduce

    prep_kernel<<<256, 256, 0, stream>>>(Wq, Wk, Wv, Wp, Wqt, Wkt, Wvt, Wpt, KV, Ksum);
    qkv_gemm<<<dim3(6, 512), 256, 0, stream>>>(x, my, Wqt, Wkt, Wvt, bq, bk, bv, Qb, Kb, Vb);
    kv_reduce<<<dim3(16, 16), 256, 0, stream>>>(Kb, Vb, KV, Ksum);
    attn_kernel<<<512, 256, 0, stream>>>(Qb, KV, Ksum, mx, Ab);
    proj_gemm<<<dim3(2, 512), 256, 0, stream>>>(Ab, Wpt, bp, out);
}